// Round 14
// baseline (411.582 us; speedup 1.0000x reference)
//
#include <hip/hip_runtime.h>
#include <hip/hip_bf16.h>

#define NN 10000
#define NE 160000
#define NZ 10
#define NC 64
#define NBES 8
#define NG 16
#define NT 2
#define NB 2048
#define NB1 2049
#define PL ((size_t)NN*64)   // plane stride (plane-major node tensors)

static constexpr float PI_F  = 3.14159265358979323846f;
static constexpr float KBES  = 0.63245553203367587f;  // sqrt(2/5)
static constexpr float S3    = 1.73205080756887729f;

// ---- workspace layout (float offsets); node tensors PLANE-MAJOR [k][n][64] ----
static constexpr size_t OFF_UVL  = 0;                        // NE*4 : (ux,uy,uz,L)
static constexpr size_t OFF_PIN  = OFF_UVL + (size_t)NE*4;
static constexpr size_t OFF_ATT  = OFF_PIN + (size_t)NN*3;
static constexpr size_t OFF_CHG  = OFF_ATT + (size_t)NN*NZ;
static constexpr size_t OFF_SHF  = OFF_CHG + (size_t)NN;
static constexpr size_t OFF_NF0  = OFF_SHF + (size_t)NE*3;   // 4 planes
static constexpr size_t OFF_NF1  = OFF_NF0 + 4*PL;
static constexpr size_t OFF_MSG0 = OFF_NF1 + 4*PL;
static constexpr size_t OFF_MSG1 = OFF_MSG0+ 4*PL;
static constexpr size_t OFF_AGG  = OFF_MSG1+ 4*PL;           // fwd agg; bwd GA1/GB0/GA0
static constexpr size_t OFF_W    = OFF_AGG + 4*PL;
static constexpr size_t O_WEMB   = OFF_W;
static constexpr size_t O_AE     = O_WEMB + 640;
static constexpr size_t O_R1     = O_AE   + 16;
static constexpr size_t O_R2     = O_R1   + 1024;
static constexpr size_t O_WMIX   = O_R2   + 8192;
static constexpr size_t O_WSC    = O_WMIX + 24576;
static constexpr size_t O_WPROD  = O_WSC  + 24576;
static constexpr size_t O_WPOLY  = O_WPROD+ 24576;
static constexpr size_t O_WE     = O_WPOLY+ 384;
static constexpr size_t O_WD     = O_WE   + 128;
static constexpr size_t OFF_ACC  = O_WD   + 128;             // zeroed region start
static constexpr size_t O_E0G    = OFF_ACC;
static constexpr size_t O_ETG    = O_E0G + 16;
static constexpr size_t O_TD     = O_ETG + 32;
static constexpr size_t O_ADP    = O_TD  + 48;
static constexpr size_t O_GPOS   = O_ADP + (size_t)NN*3;     // atomically accumulated
static constexpr size_t ACC_FLOATS = 96 + (size_t)NN*6;      // e0g..adp..gpos
static constexpr size_t O_EN0    = O_GPOS + (size_t)NN*3;
static constexpr size_t O_EN1    = O_EN0 + NN;
static constexpr size_t O_E0N    = O_EN1 + NN;
static constexpr size_t O_FLAG   = O_E0N + NN;
static constexpr size_t O_GVP    = O_FLAG + 4;
static constexpr size_t O_GNFC   = O_GVP + 64;
static constexpr size_t O_TW     = O_GNFC + 64;              // 2 layers x NB1 x 64
static constexpr size_t O_TQ     = O_TW + (size_t)2*NB1*64;
static constexpr size_t O_OFFR   = O_TQ + (size_t)2*NB1*64;  // ints from here
static constexpr size_t O_OFFS   = O_OFFR + (NN+1);
static constexpr size_t O_CURR   = O_OFFS + (NN+1);
static constexpr size_t O_CURS   = O_CURR + NN;
static constexpr size_t O_LISTR  = O_CURS + NN;
static constexpr size_t O_LISTS  = O_LISTR + (size_t)NE;
static constexpr size_t WS_FLOATS= O_LISTS + (size_t)NE;     // ~63 MB

__device__ __forceinline__ float rlane(float v, int l){
  return __int_as_float(__builtin_amdgcn_readlane(__float_as_int(v), l));
}

// ---------- dtype detection ----------
__global__ void k_detect(const unsigned* __restrict__ raw, int* __restrict__ flag){
  __shared__ int found;
  if (threadIdx.x == 0) found = 0;
  __syncthreads();
  for (int i = threadIdx.x; i < 4096; i += 256){
    unsigned w = raw[i];
    if (w == 0x00003F80u || w == 0x3F803F80u) found = 1;
  }
  __syncthreads();
  if (threadIdx.x == 0) flag[0] = found;
}

// ---------- fused loader ----------
static constexpr int LD_CNT[14] = {NN*3, NN*NZ, NN, NE*3, NZ*64, NZ, NT*NBES*64, NT*64*64,
                                   NT*3*64*64, NT*3*64*64, NT*64*3, NT*3*64*64, NT*64, NT*64};
static constexpr int LD_TOTAL = NN*3 + NN*NZ + NN + NE*3 + NZ*64 + NZ + NT*NBES*64 + NT*64*64
                              + 3*(NT*3*64*64) + NT*64*3 + 4*(NT*64) - NT*64*2;
__global__ __launch_bounds__(256) void k_load_all(
    const void* s0, const void* s1, const void* s2, const void* s3, const void* s4,
    const void* s5, const void* s6, const void* s7, const void* s8, const void* s9,
    const void* s10, const void* s11, const void* s12, const void* s13,
    float* __restrict__ ws, const int* __restrict__ flag){
  const void* srcs[14] = {s0,s1,s2,s3,s4,s5,s6,s7,s8,s9,s10,s11,s12,s13};
  const size_t dsts[14] = {OFF_PIN, OFF_ATT, OFF_CHG, OFF_SHF, O_WEMB, O_AE, O_R1, O_R2,
                           O_WMIX, O_WSC, O_WPOLY, O_WPROD, O_WE, O_WD};
  int i = blockIdx.x*256 + threadIdx.x;
  int seg = -1, off = i;
  #pragma unroll
  for (int j = 0; j < 14; ++j){
    if (seg < 0){
      if (off < LD_CNT[j]) seg = j;
      else off -= LD_CNT[j];
    }
  }
  if (seg < 0) return;
  float v = flag[0] ? __bfloat162float(((const __hip_bfloat16*)srcs[seg])[off])
                    : ((const float*)srcs[seg])[off];
  ws[dsts[seg] + off] = v;
}

// ================= k_prep: geom + radial tables + node init + bwd head =================
// block ranges: [0,625) geom | [625,1650) tables | [1650,4150) init | 4150 bwd_head
__global__ __launch_bounds__(256) void k_prep(float* __restrict__ ws, const int* __restrict__ ei){
  int b = blockIdx.x;
  if (b < 625){
    // ---- edge geometry + live-edge counting ----
    int e = b*256 + threadIdx.x;
    if (e >= NE) return;
    const float* pos    = ws + OFF_PIN;
    const float* shifts = ws + OFF_SHF;
    float* uvl = ws + OFF_UVL;
    int* cntr = (int*)(ws + O_CURR);
    int* cnts = (int*)(ws + O_CURS);
    int s = ei[e], r = ei[NE + e];
    float vx = pos[s*3+0] - pos[r*3+0] + shifts[(size_t)e*3+0];
    float vy = pos[s*3+1] - pos[r*3+1] + shifts[(size_t)e*3+1];
    float vz = pos[s*3+2] - pos[r*3+2] + shifts[(size_t)e*3+2];
    float L = sqrtf(vx*vx + vy*vy + vz*vz + 1e-12f);
    float inv = 1.f / L;
    uvl[(size_t)e*4+0] = vx*inv; uvl[(size_t)e*4+1] = vy*inv;
    uvl[(size_t)e*4+2] = vz*inv; uvl[(size_t)e*4+3] = L;
    if (L < 5.f){
      atomicAdd(&cntr[r], 1);
      atomicAdd(&cnts[s], 1);
    }
  } else if (b < 1650){
    // ---- radial tables ----
    int lane = threadIdx.x & 63;
    int task = (b-625)*4 + (threadIdx.x >> 6);
    if (task >= 2*NB1) return;
    int t = task / NB1, node = task % NB1;
    const float* R1 = ws + O_R1 + (size_t)t*512;
    const float* R2 = ws + O_R2 + (size_t)t*4096;
    float* TW = ws + O_TW;
    float* TQ = ws + O_TQ;
    float r1c[8];
    #pragma unroll
    for (int j = 0; j < 8; ++j) r1c[j] = R1[j*64 + lane];
    float L = fmaxf((float)node * (5.f/NB), 1e-6f);
    float ur = L*0.2f;
    float ef[8], dd[8];
    if (ur < 1.f){
      float u2=ur*ur, u4=u2*u2, u5=u4*ur;
      float fc = 1.f - 21.f*u5 + 35.f*u5*ur - 15.f*u5*u2;
      float omu = 1.f - ur;
      float dfc = -105.f*u4*omu*omu;
      float invr = 1.f/(L + 1e-9f);
      #pragma unroll
      for (int bb = 0; bb < 8; ++bb){
        float nb = (float)(bb+1);
        float arg = nb*PI_F*ur;
        float sn = __sinf(arg), cs = __cosf(arg);
        float bes = KBES*sn*invr;
        float dbes = KBES*(nb*PI_F*0.2f)*cs*invr - bes*invr;
        ef[bb] = bes*fc;
        dd[bb] = dbes*fc + bes*dfc*0.2f;
      }
    } else {
      #pragma unroll
      for (int bb = 0; bb < 8; ++bb){ ef[bb] = 0.f; dd[bb] = 0.f; }
    }
    float a = 0.f, tt = 0.f;
    #pragma unroll
    for (int bb = 0; bb < 8; ++bb){ a = fmaf(ef[bb], r1c[bb], a); tt = fmaf(r1c[bb], dd[bb], tt); }
    float sg = 1.f/(1.f + __expf(-a));
    float sl = a*sg;
    float q  = sg*fmaf(a, 1.f - sg, 1.f)*tt;
    float r2c[64];
    #pragma unroll
    for (int j = 0; j < 64; ++j) r2c[j] = R2[j*64 + lane];
    float W0=0.f, W1=0.f, Q0=0.f, Q1=0.f;
    #pragma unroll
    for (int j = 0; j < 64; j += 2){
      W0 = fmaf(rlane(sl, j  ), r2c[j  ], W0);
      W1 = fmaf(rlane(sl, j+1), r2c[j+1], W1);
      Q0 = fmaf(rlane(q,  j  ), r2c[j  ], Q0);
      Q1 = fmaf(rlane(q,  j+1), r2c[j+1], Q1);
    }
    size_t idx = ((size_t)t*NB1 + node)*64 + lane;
    TW[idx] = W0+W1;
    TQ[idx] = Q0+Q1;
  } else if (b < 4150){
    // ---- node init (plane-major) ----
    int lane = threadIdx.x & 63;
    int n = (b-1650)*4 + (threadIdx.x >> 6);
    if (n >= NN) return;
    const float* attrs = ws + OFF_ATT;
    const float* Wemb  = ws + O_WEMB;
    const float* ae    = ws + O_AE;
    float* nf0 = ws + OFF_NF0;
    float* e0n = ws + O_E0N;
    float acc = 0.f;
    #pragma unroll
    for (int z = 0; z < NZ; ++z) acc = fmaf(attrs[(size_t)n*NZ+z], Wemb[z*64+lane], acc);
    size_t base = (size_t)n*64 + lane;
    nf0[base] = acc;
    #pragma unroll
    for (int k = 1; k < 4; ++k) nf0[base + (size_t)k*PL] = 0.f;
    if (lane == 0){
      float e = 0.f;
      #pragma unroll
      for (int z = 0; z < NZ; ++z) e = fmaf(attrs[(size_t)n*NZ+z], ae[z], e);
      e0n[n] = e;
    }
  } else {
    // ---- backward head: row-major reads of untransposed weights ----
    int d = threadIdx.x;
    if (d >= 64) return;
    const float* WPROD1 = ws + O_WPROD + 12288;   // t=1, l=0
    const float* WSC1   = ws + O_WSC   + 12288;
    const float* we1 = ws + O_WE + 64;
    const float* we0 = ws + O_WE;
    float a = 0.f, bb = 0.f;
    #pragma unroll
    for (int c = 0; c < 64; ++c){
      float w = we1[c];
      a  = fmaf(w, WPROD1[d*64+c], a);   // = WPRODT1[c][d]
      bb = fmaf(w, WSC1[d*64+c], bb);
    }
    ws[O_GVP + d] = a;
    ws[O_GNFC + d] = bb + we0[d];
  }
}

// ================= LDS-staged prefix scan =================
__global__ __launch_bounds__(256) void k_csr_scan(
    int* __restrict__ cntr, int* __restrict__ cnts,
    int* __restrict__ offr, int* __restrict__ offs_){
  __shared__ int lds[NN];
  __shared__ int part[256];
  for (int q = 0; q < 2; ++q){
    int* c   = q ? cnts  : cntr;
    int* off = q ? offs_ : offr;
    for (int i = threadIdx.x; i < NN; i += 256) lds[i] = c[i];
    __syncthreads();
    const int chunk = (NN + 255)/256;
    int lo = threadIdx.x*chunk, hi = lo+chunk; if (hi > NN) hi = NN; if (lo > NN) lo = NN;
    int s = 0;
    for (int i = lo; i < hi; ++i) s += lds[i];
    part[threadIdx.x] = s;
    __syncthreads();
    for (int o = 1; o < 256; o <<= 1){
      int v = (threadIdx.x >= o) ? part[threadIdx.x-o] : 0;
      __syncthreads();
      part[threadIdx.x] += v;
      __syncthreads();
    }
    int run = (threadIdx.x == 0) ? 0 : part[threadIdx.x-1];
    for (int i = lo; i < hi; ++i){
      int ci = lds[i];
      off[i] = run; c[i] = run;
      run += ci;
    }
    if (threadIdx.x == 255) off[NN] = run;
    __syncthreads();
  }
}

// ---------- fill: live edges only ----------
__global__ void k_csr_fill(const int* __restrict__ ei, const float* __restrict__ uvl,
                           int* __restrict__ curr, int* __restrict__ curs,
                           int* __restrict__ listr, int* __restrict__ lists){
  int e = blockIdx.x*256 + threadIdx.x;
  if (e >= NE) return;
  if (uvl[(size_t)e*4+3] >= 5.f) return;
  int pr = atomicAdd(&curr[ei[NE+e]], 1); listr[pr] = e;
  int ps = atomicAdd(&curs[ei[e]], 1);    lists[ps] = e;
}

// ================= aggregation via live receiver CSR (plane-major out) =================
__global__ __launch_bounds__(256) void k_agg(
    const float* __restrict__ TW, const float* __restrict__ uvl,
    const float* __restrict__ h0, const int* __restrict__ ei,
    const int* __restrict__ offr, const int* __restrict__ listr,
    float* __restrict__ agg){
  int lane = threadIdx.x & 63;
  int wid = blockIdx.x*4 + (threadIdx.x >> 6);
  int nw  = gridDim.x*4;
  for (int n = wid; n < NN; n += nw){
    int lo = offr[n], hi = offr[n+1];
    float acc0=0.f, acc1=0.f, acc2=0.f, acc3=0.f;
    for (int i = lo; i < hi; ++i){
      int e = __builtin_amdgcn_readfirstlane(listr[i]);
      int s = __builtin_amdgcn_readfirstlane(ei[e]);
      float ux = uvl[(size_t)e*4], uy = uvl[(size_t)e*4+1], uz = uvl[(size_t)e*4+2];
      float L  = uvl[(size_t)e*4+3];
      float pos = L*(NB/5.f);
      int bi = (int)pos;
      float f = pos - (float)bi;
      const float* T = TW + (size_t)bi*64 + lane;
      float w = fmaf(T[64]-T[0], f, T[0]);
      float wh = w * h0[(size_t)s*64 + lane];
      acc0 += wh;
      acc1 = fmaf(wh, S3*ux, acc1);
      acc2 = fmaf(wh, S3*uy, acc2);
      acc3 = fmaf(wh, S3*uz, acc3);
    }
    size_t ob = (size_t)n*64 + lane;
    agg[ob]        = acc0*(1.f/16.f);
    agg[ob+PL]     = acc1*(1.f/16.f);
    agg[ob+2*PL]   = acc2*(1.f/16.f);
    agg[ob+3*PL]   = acc3*(1.f/16.f);
  }
}

// ================= per-l linear (mix), plane-major =================
__global__ __launch_bounds__(256) void k_lin2(
    const float* __restrict__ in, const float* __restrict__ W3, float* __restrict__ out){
  int k = blockIdx.y;
  int l = (k==0) ? 0 : 1;
  const float* W = W3 + (size_t)l*4096;
  int lane = threadIdx.x & 63;
  float wcol[64];
  #pragma unroll
  for (int j = 0; j < 64; ++j) wcol[j] = W[j*64 + lane];
  int wid = blockIdx.x*4 + (threadIdx.x >> 6);
  int nw  = gridDim.x*4;
  const float* inp = in + (size_t)k*PL;
  float* outp = out + (size_t)k*PL;
  for (int n = wid; n < NN; n += nw){
    float x = inp[(size_t)n*64 + lane];
    float a0 = 0.f, a1 = 0.f, a2 = 0.f, a3 = 0.f;
    #pragma unroll
    for (int j = 0; j < 64; j += 4){
      a0 = fmaf(rlane(x, j  ), wcol[j  ], a0);
      a1 = fmaf(rlane(x, j+1), wcol[j+1], a1);
      a2 = fmaf(rlane(x, j+2), wcol[j+2], a2);
      a3 = fmaf(rlane(x, j+3), wcol[j+3], a3);
    }
    outp[(size_t)n*64 + lane] = (a0+a1) + (a2+a3);
  }
}

// ================= fused layer tail (plane-major; optional nf_out write) =================
__global__ __launch_bounds__(256) void k_tail(
    const float* __restrict__ nf_in, const float* __restrict__ msg,
    const float* __restrict__ Wsc, const float* __restrict__ Wprod, const float* __restrict__ wp,
    const float* __restrict__ we, const float* __restrict__ wd,
    float* __restrict__ nf_out, float* __restrict__ en, float* __restrict__ adp, int write_nf){
  int lane = threadIdx.x & 63;
  int k = threadIdx.x >> 6;
  int l = (k==0) ? 0 : 1;
  float wcs[64], wcp[64];
  #pragma unroll
  for (int j = 0; j < 64; ++j){
    wcs[j] = Wsc[(size_t)l*4096 + j*64 + lane];
    wcp[j] = Wprod[(size_t)l*4096 + j*64 + lane];
  }
  float p0 = wp[lane*3], p1 = wp[lane*3+1], p2 = wp[lane*3+2];
  float rw = (k==0) ? we[lane] : wd[lane];
  const float* msgk = msg + (size_t)k*PL;
  const float* nfk  = nf_in + (size_t)k*PL;
  float* outk = nf_out + (size_t)k*PL;
  for (int n = blockIdx.x; n < NN; n += gridDim.x){
    size_t base = (size_t)n*64 + lane;
    float s0 = msg[base];
    float xm = (k==0) ? s0 : msgk[base];
    float xg = xm * fmaf(fmaf(p2, s0, p1), s0, p0);
    float xs = nfk[base];
    float a0=0.f, a1=0.f, b0=0.f, b1=0.f;
    #pragma unroll
    for (int j = 0; j < 64; j += 2){
      a0 = fmaf(rlane(xs, j  ), wcs[j  ], a0);
      a1 = fmaf(rlane(xs, j+1), wcs[j+1], a1);
      b0 = fmaf(rlane(xg, j  ), wcp[j  ], b0);
      b1 = fmaf(rlane(xg, j+1), wcp[j+1], b1);
    }
    float out = (a0+a1) + (b0+b1);
    if (write_nf) outk[base] = out;
    float red = out * rw;
    #pragma unroll
    for (int o = 32; o; o >>= 1) red += __shfl_xor(red, o, 64);
    if (lane == 0){
      if (k == 0) en[n] = red;
      else        adp[n*3 + (k-1)] += red;
    }
  }
}

// ================= t=1 backward chain (row-major weight reads) =================
__global__ __launch_bounds__(256) void k_gback1(
    const float* __restrict__ gvp, const float* __restrict__ msg1, const float* __restrict__ wp,
    const float* __restrict__ WMIX1, float* __restrict__ out){
  int lane = threadIdx.x & 63;
  float wcol[64];
  #pragma unroll
  for (int j = 0; j < 64; ++j) wcol[j] = WMIX1[lane*64 + j];   // row lane of WMIX t1 l0
  float g = gvp[lane];
  float p0 = wp[lane*3], p1 = wp[lane*3+1], p2 = wp[lane*3+2];
  int wid = blockIdx.x*4 + (threadIdx.x >> 6);
  int nw  = gridDim.x*4;
  for (int n = wid; n < NN; n += nw){
    float s0 = msg1[(size_t)n*64 + lane];
    float poly = fmaf(fmaf(p2, s0, p1), s0, p0);
    float dp   = fmaf(2.f*p2, s0, p1);
    float gb = g*fmaf(s0, dp, poly);
    float a0=0.f, a1=0.f, a2=0.f, a3=0.f;
    #pragma unroll
    for (int j = 0; j < 64; j += 4){
      a0 = fmaf(rlane(gb, j  ), wcol[j  ], a0);
      a1 = fmaf(rlane(gb, j+1), wcol[j+1], a1);
      a2 = fmaf(rlane(gb, j+2), wcol[j+2], a2);
      a3 = fmaf(rlane(gb, j+3), wcol[j+3], a3);
    }
    out[(size_t)n*64 + lane] = (a0+a1) + (a2+a3);
  }
}

// ================= t=0 backward chain (row-major weight reads) =================
__global__ __launch_bounds__(256) void k_gback0(
    const float* __restrict__ gnf0, const float* __restrict__ msg0, const float* __restrict__ wp,
    const float* __restrict__ WPROD0, const float* __restrict__ WMIX0,
    float* __restrict__ out){
  int lane = threadIdx.x & 63;
  float wcp[64], wcm[64];
  #pragma unroll
  for (int j = 0; j < 64; ++j){
    wcp[j] = WPROD0[lane*64 + j];   // row lane
    wcm[j] = WMIX0[lane*64 + j];
  }
  float p0 = wp[lane*3], p1 = wp[lane*3+1], p2 = wp[lane*3+2];
  int wid = blockIdx.x*4 + (threadIdx.x >> 6);
  int nw  = gridDim.x*4;
  for (int n = wid; n < NN; n += nw){
    float x = gnf0[(size_t)n*64 + lane];
    float a0=0.f, a1=0.f;
    #pragma unroll
    for (int j = 0; j < 64; j += 2){
      a0 = fmaf(rlane(x, j  ), wcp[j  ], a0);
      a1 = fmaf(rlane(x, j+1), wcp[j+1], a1);
    }
    float gmp = a0+a1;
    float s0 = msg0[(size_t)n*64 + lane];
    float poly = fmaf(fmaf(p2, s0, p1), s0, p0);
    float dp   = fmaf(2.f*p2, s0, p1);
    float gb = gmp*fmaf(s0, dp, poly);
    float b0=0.f, b1=0.f;
    #pragma unroll
    for (int j = 0; j < 64; j += 2){
      b0 = fmaf(rlane(gb, j  ), wcm[j  ], b0);
      b1 = fmaf(rlane(gb, j+1), wcm[j+1], b1);
    }
    out[(size_t)n*64 + lane] = b0+b1;
  }
}

// ================= fused both-layer edge backward; atomic force scatter =================
__global__ __launch_bounds__(256) void k_bwdE2(
    const float* __restrict__ TQ, const float* __restrict__ uvl,
    const float* __restrict__ h0, const float* __restrict__ h1,
    const float* __restrict__ ga0, const float* __restrict__ ga1,
    const int* __restrict__ ei, const int* __restrict__ lists,
    const int* __restrict__ nlive_ptr, float* __restrict__ gpos){
  int lane = threadIdx.x & 63;
  int wid = blockIdx.x*4 + (threadIdx.x >> 6);
  int nw  = gridDim.x*4;
  int nlive = nlive_ptr[0];
  for (int i = wid; i < nlive; i += nw){
    int e = __builtin_amdgcn_readfirstlane(lists[i]);
    int s = __builtin_amdgcn_readfirstlane(ei[e]);
    int r = __builtin_amdgcn_readfirstlane(ei[NE+e]);
    float L  = uvl[(size_t)e*4+3];
    float pos = L*(NB/5.f);
    int bi = (int)pos;
    float f = pos - (float)bi;
    const float* T0 = TQ + (size_t)bi*64 + lane;
    const float* T1 = T0 + (size_t)NB1*64;
    float Q0 = fmaf(T0[64]-T0[0], f, T0[0]);
    float Q1 = fmaf(T1[64]-T1[0], f, T1[0]);
    float rr = Q0*h0[(size_t)s*64 + lane]*ga0[(size_t)r*64 + lane]
             + Q1*h1[(size_t)s*64 + lane]*ga1[(size_t)r*64 + lane];
    rr *= (1.f/16.f);
    #pragma unroll
    for (int o = 32; o; o >>= 1) rr += __shfl_xor(rr, o, 64);
    if (lane < 3){
      float comp = rr*uvl[(size_t)e*4 + lane];
      atomicAdd(&gpos[s*3 + lane],  comp);
      atomicAdd(&gpos[r*3 + lane], -comp);
    }
  }
}

// ================= gh gather via live sender CSR =================
__global__ __launch_bounds__(256) void k_ghgather0(
    const float* __restrict__ TW, const float* __restrict__ uvl, const float* __restrict__ gagg0,
    const int* __restrict__ ei, const int* __restrict__ offs_, const int* __restrict__ lists,
    const float* __restrict__ gnfc, float* __restrict__ out){
  int lane = threadIdx.x & 63;
  int wid = blockIdx.x*4 + (threadIdx.x >> 6);
  int nw  = gridDim.x*4;
  for (int n = wid; n < NN; n += nw){
    int lo = offs_[n], hi = offs_[n+1];
    float acc = 0.f;
    for (int i = lo; i < hi; ++i){
      int e = __builtin_amdgcn_readfirstlane(lists[i]);
      int r = __builtin_amdgcn_readfirstlane(ei[NE+e]);
      float L = uvl[(size_t)e*4+3];
      float pos = L*(NB/5.f);
      int bi = (int)pos;
      float f = pos - (float)bi;
      const float* T = TW + (size_t)bi*64 + lane;
      float w = fmaf(T[64]-T[0], f, T[0]);
      acc = fmaf(w, gagg0[(size_t)r*64 + lane], acc);
    }
    out[(size_t)n*64 + lane] = gnfc[lane] + acc*(1.f/16.f);
  }
}

// ================= segmented final reduction =================
__global__ void k_reduce(const float* __restrict__ e0n, const float* __restrict__ en0,
                         const float* __restrict__ en1, const float* __restrict__ adp,
                         const float* __restrict__ q, const float* __restrict__ pos,
                         const int* __restrict__ batch, float* __restrict__ e0g,
                         float* __restrict__ Etg, float* __restrict__ td){
  int n = blockIdx.x*256 + threadIdx.x;
  int lane = threadIdx.x & 63;
  bool valid = (n < NN);
  int g = valid ? batch[n] : -1;
  float v0=0.f, v1=0.f, v2=0.f, tx=0.f, ty=0.f, tz=0.f;
  if (valid){
    v0 = e0n[n]; v1 = en0[n]; v2 = en1[n];
    float qq = q[n];
    tx = adp[n*3+0] + qq*pos[n*3+0];
    ty = adp[n*3+1] + qq*pos[n*3+1];
    tz = adp[n*3+2] + qq*pos[n*3+2];
  }
  int g0 = __shfl(g, 0, 64), g63 = __shfl(g, 63, 64);
  if (g0 == g63 && g0 >= 0){
    #pragma unroll
    for (int o = 32; o; o >>= 1){
      v0 += __shfl_xor(v0, o, 64); v1 += __shfl_xor(v1, o, 64); v2 += __shfl_xor(v2, o, 64);
      tx += __shfl_xor(tx, o, 64); ty += __shfl_xor(ty, o, 64); tz += __shfl_xor(tz, o, 64);
    }
    if (lane == 0){
      atomicAdd(&e0g[g0], v0); atomicAdd(&Etg[g0], v1); atomicAdd(&Etg[16+g0], v2);
      atomicAdd(&td[g0*3+0], tx); atomicAdd(&td[g0*3+1], ty); atomicAdd(&td[g0*3+2], tz);
    }
  } else if (valid){
    atomicAdd(&e0g[g], v0); atomicAdd(&Etg[g], v1); atomicAdd(&Etg[16+g], v2);
    atomicAdd(&td[g*3+0], tx); atomicAdd(&td[g*3+1], ty); atomicAdd(&td[g*3+2], tz);
  }
}

__global__ void k_writeout(const float* __restrict__ e0g, const float* __restrict__ Etg,
                           const float* __restrict__ td, const float* __restrict__ adp,
                           const float* __restrict__ gpos, void* __restrict__ outv,
                           const int* __restrict__ flag){
  int i = blockIdx.x*256 + threadIdx.x;
  const int total = NG + NG*3 + NN*3 + NG*3 + NN*3; // 60112
  if (i >= total) return;
  float v;
  if (i < 16){
    v = e0g[i] + Etg[i] + Etg[16+i];
  } else if (i < 64){
    int j = i - 16; int g = j/3, t = j - g*3;
    v = (t == 0) ? e0g[g] : Etg[(t-1)*16 + g];
  } else if (i < 64 + NN*3){
    v = -gpos[i-64];
  } else if (i < 64 + NN*3 + 48){
    v = td[i - (64 + NN*3)];
  } else {
    v = adp[i - (64 + NN*3 + 48)];
  }
  if (flag[0]) ((__hip_bfloat16*)outv)[i] = __float2bfloat16(v);
  else         ((float*)outv)[i] = v;
}

extern "C" void kernel_launch(void* const* d_in, const int* in_sizes, int n_in,
                              void* d_out, int out_size, void* d_ws, size_t ws_size,
                              hipStream_t stream) {
  if (ws_size < WS_FLOATS*sizeof(float)) return; // ~63 MB
  const int* ei    = (const int*)d_in[14];
  const int* batch = (const int*)d_in[15];
  float* ws = (float*)d_ws;
  int* flag = (int*)(ws + O_FLAG);

  int* offr  = (int*)(ws + O_OFFR);
  int* offs_ = (int*)(ws + O_OFFS);
  int* curr  = (int*)(ws + O_CURR);
  int* curs  = (int*)(ws + O_CURS);
  int* listr = (int*)(ws + O_LISTR);
  int* lists = (int*)(ws + O_LISTS);

  hipMemsetAsync(ws + OFF_ACC, 0, ACC_FLOATS*sizeof(float), stream);   // e0g..gpos
  hipMemsetAsync(curr, 0, 2*NN*sizeof(int), stream);
  k_detect<<<1, 256, 0, stream>>>((const unsigned*)d_in[1], flag);
  k_load_all<<<(LD_TOTAL+255)/256, 256, 0, stream>>>(
      d_in[0], d_in[1], d_in[2], d_in[3], d_in[4], d_in[5], d_in[6], d_in[7],
      d_in[8], d_in[9], d_in[10], d_in[11], d_in[12], d_in[13], ws, flag);

  k_prep<<<4151, 256, 0, stream>>>(ws, ei);

  k_csr_scan<<<1, 256, 0, stream>>>(curr, curs, offr, offs_);
  k_csr_fill<<<(NE+255)/256, 256, 0, stream>>>(ei, ws+OFF_UVL, curr, curs, listr, lists);

  const size_t NF[2]  = {OFF_NF0, OFF_NF1};
  const size_t MSG[2] = {OFF_MSG0, OFF_MSG1};
  dim3 ling(256, 4);
  float* GA1 = ws + OFF_AGG;                        // t=1 gagg (kept)
  float* GB0 = ws + OFF_AGG + PL;                   // gnf t=0
  float* GA0 = ws + OFF_AGG + 2*PL;                 // t=0 gagg

  // ---------- forward ----------
  for (int t = 0; t < NT; ++t){
    k_agg<<<1024, 256, 0, stream>>>(ws+O_TW + (size_t)t*NB1*64, ws+OFF_UVL,
                                    ws+NF[t], ei, offr, listr, ws+OFF_AGG);
    k_lin2<<<ling, 256, 0, stream>>>(ws+OFF_AGG, ws+O_WMIX + (size_t)t*12288, ws+MSG[t]);
    k_tail<<<1024, 256, 0, stream>>>(ws+NF[t], ws+MSG[t],
                                     ws+O_WSC + (size_t)t*12288, ws+O_WPROD + (size_t)t*12288,
                                     ws+O_WPOLY + (size_t)t*192, ws+O_WE + (size_t)t*64,
                                     ws+O_WD + (size_t)t*64,
                                     ws+NF[(t+1)&1] /*unused when write_nf=0*/,
                                     ws + (t ? O_EN1 : O_EN0), ws+O_ADP, t == 0 ? 1 : 0);
  }

  // ---------- backward (k=0 plane only) ----------
  k_gback1<<<1024, 256, 0, stream>>>(ws+O_GVP, ws+MSG[1], ws+O_WPOLY+192,
                                     ws+O_WMIX+12288, GA1);
  k_ghgather0<<<1024, 256, 0, stream>>>(ws+O_TW + (size_t)NB1*64, ws+OFF_UVL, GA1, ei,
                                        offs_, lists, ws+O_GNFC, GB0);
  k_gback0<<<1024, 256, 0, stream>>>(GB0, ws+MSG[0], ws+O_WPOLY,
                                     ws+O_WPROD, ws+O_WMIX, GA0);
  k_bwdE2<<<2048, 256, 0, stream>>>(ws+O_TQ, ws+OFF_UVL,
                                    ws+OFF_NF0, ws+OFF_NF1, GA0, GA1,
                                    ei, lists, offs_ + NN, ws+O_GPOS);

  k_reduce<<<(NN+255)/256, 256, 0, stream>>>(ws+O_E0N, ws+O_EN0, ws+O_EN1, ws+O_ADP,
                                             ws+OFF_CHG, ws+OFF_PIN, batch,
                                             ws+O_E0G, ws+O_ETG, ws+O_TD);
  k_writeout<<<(60112+255)/256, 256, 0, stream>>>(ws+O_E0G, ws+O_ETG, ws+O_TD, ws+O_ADP, ws+O_GPOS, d_out, flag);
}